// Round 12
// baseline (153.094 us; speedup 1.0000x reference)
//
#include <hip/hip_runtime.h>
#include <math.h>

typedef float v4f __attribute__((ext_vector_type(4)));

// ---------------- geometry ----------------
#define SD 64
#define CC 64
#define EE 320
#define NS 27
#define NPAIR 351

#define NCHUNK 27               // chunks per mid node, 400 rows each
#define AGG_BLKS (27 * NCHUNK)  // 729
#define NRCHUNK 216             // root agg chunks, 50 rows each

// ws layout (floats)
#define WS_QKV   0                       // 25920
#define WS_ENT   25920                   // 22464 -> 48384
#define WS_MIDP  48384                   // 729*400 = 291600 -> 339984
#define WS_CF    339984                  // 10800 -> 350784
#define WS_ROOTP 350784                  // 216*400 = 86400 -> 437184
#define WS_HPM   437184                  // 27*4*64 = 6912 -> 444096
#define WS_CTR   444096                  // 32 ints
#define WS_O     444128                  // 8640 -> 452768
#define WS_AVG   452768                  // 64
// ctr indices: [0..26] per-node mid quarters, [31] rootagg chunks

// direct global->LDS DMA, 16B per lane per wave-call (dest = uniform base + lane*16)
__device__ __forceinline__ void gload_lds16(const float* g, float* l) {
    __builtin_amdgcn_global_load_lds(
        (const __attribute__((address_space(1))) unsigned int*)(g),
        (__attribute__((address_space(3))) unsigned int*)(l),
        16, 0, 0);
}

// ================= K1 (512 threads): mid_agg | granger | qkv | ent =================
// blocks: [0,729) agg, [729,731) granger, [731,782) qkv, [782,870) ent

__device__ void dev_mid_agg(int blk, const float* __restrict__ W,
                            const float* __restrict__ leaf, float* __restrict__ partial) {
    __shared__ float c_l[400];
    __shared__ __align__(16) float Wl[2][6400];   // 2 x (16 rows x 400 cols)
    int t = threadIdx.x;
    int n = blk / NCHUNK, chunk = blk % NCHUNK;
    int wv = t >> 6, lane = t & 63;
    const float* Wg = W + (size_t)(n * 10800 + chunk * 400) * 400;  // 400-row chunk base
    if (t < 400) c_l[t] = leaf[n * 10800 + chunk * 400 + t];
    // stage tile 0 (16 rows = 25600 B = 25 wave-chunks of 1024 B)
    for (int c = wv; c < 25; c += 8)
        gload_lds16(Wg + c * 256 + lane * 4, &Wl[0][c * 256]);
    __syncthreads();
    float acc = 0.0f;
    int buf = 0;
    for (int tile = 0; tile < 25; ++tile) {
        if (tile < 24) {
            const float* Wt = Wg + (size_t)(tile + 1) * 6400;
            for (int c = wv; c < 25; c += 8)
                gload_lds16(Wt + c * 256 + lane * 4, &Wl[buf ^ 1][c * 256]);
        }
        if (t < 400) {
            #pragma unroll
            for (int r = 0; r < 16; ++r)
                acc += c_l[tile * 16 + r] * Wl[buf][r * 400 + t];
        }
        __syncthreads();   // drains global_load_lds (vmcnt) + protects buf reuse
        buf ^= 1;
    }
    if (t < 400) partial[(size_t)blk * 400 + t] = acc;
}

__device__ void dev_granger(int blk, const float* __restrict__ x, const float* __restrict__ h,
                            const float* __restrict__ gW, const float* __restrict__ gb,
                            float* __restrict__ out) {
    int idx = blk * 512 + threadIdx.x;
    if (idx >= NS * NS) return;
    int i = idx / NS, j = idx % NS;
    const float* hr = h + j * 320;
    const float* xr = x + i * 320;
    float acc = gb[0];
    for (int k = 0; k < 320; ++k) acc += hr[k] * gW[k] + xr[k] * gW[320 + k];
    float sig = 1.0f / (1.0f + expf(-acc));
    out[idx] = (i == j) ? 0.0f : sig;
}

__device__ void dev_qkv(int blk, const float* __restrict__ x, const float* __restrict__ W,
                        const float* __restrict__ b, float* __restrict__ qkv) {
    int idx = blk * 512 + threadIdx.x;
    if (idx >= NS * 960) return;
    int i = idx / 960, c = idx % 960;
    const float4* xr = (const float4*)(x + i * 320);
    const float4* wr = (const float4*)(W + (size_t)c * 320);
    float acc = b[c];
    #pragma unroll 8
    for (int k = 0; k < 80; ++k) {
        float4 a = xr[k], w = wr[k];
        acc += a.x * w.x + a.y * w.y + a.z * w.z + a.w * w.w;
    }
    qkv[idx] = acc;
}

__device__ void dev_ent(int blk, const float* __restrict__ q_real,
                        const float* __restrict__ W1, const float* __restrict__ b1,
                        const float* __restrict__ W2, const float* __restrict__ b2,
                        float* __restrict__ ent_scaled) {
    __shared__ float comb[4][128];
    __shared__ float hid[4][64];
    int t = threadIdx.x;
    int sub = t >> 7, lt = t & 127;
    int p = blk * 4 + sub;
    bool pv = (p < NPAIR);
    bool valid = pv && (lt < 64);
    int i = 0, jj = 0;
    if (pv) {
        int rem = p;
        while (rem >= 26 - i) { rem -= 26 - i; ++i; }
        jj = i + 1 + rem;
    }
    float qa = 0.f, qb = 0.f;
    if (valid) { qa = q_real[i * CC + lt]; qb = q_real[jj * CC + lt]; }
    float sa = qa, sb = qb;
    #pragma unroll
    for (int off = 32; off; off >>= 1) { sa += __shfl_xor(sa, off); sb += __shfl_xor(sb, off); }
    float coupling = expf(-fabsf(sa - sb) / (500.0f + 1e-6f));
    if (valid) { comb[sub][lt] = qa; comb[sub][64 + lt] = qb; }
    __syncthreads();
    if (valid) {
        float hs = b1[lt];
        for (int ii = 0; ii < 128; ++ii) hs += comb[sub][ii] * W1[ii * 64 + lt];
        hid[sub][lt] = fmaxf(hs, 0.0f);
    }
    __syncthreads();
    if (valid) {
        float e = b2[lt];
        for (int k = 0; k < 64; ++k) e += hid[sub][k] * W2[k * 64 + lt];
        ent_scaled[p * 64 + lt] = e * coupling;
    }
}

__global__ __launch_bounds__(512) void k_stage1(
    const float* __restrict__ mid_agg_W, const float* __restrict__ leaf,
    const float* __restrict__ node, const float* __restrict__ hist,
    const float* __restrict__ gW, const float* __restrict__ gb,
    const float* __restrict__ mha_in_W, const float* __restrict__ mha_in_b,
    const float* __restrict__ q_real,
    const float* __restrict__ ent_W1, const float* __restrict__ ent_b1,
    const float* __restrict__ ent_W2, const float* __restrict__ ent_b2,
    float* __restrict__ mid_partial, float* __restrict__ out_causal,
    float* __restrict__ qkv, float* __restrict__ ent_scaled,
    int* __restrict__ ctrs) {
    int blk = blockIdx.x;
    if (blk == 0 && threadIdx.x >= 480) ctrs[threadIdx.x - 480] = 0;
    if (blk < AGG_BLKS)           dev_mid_agg(blk, mid_agg_W, leaf, mid_partial);
    else if (blk < AGG_BLKS + 2)  dev_granger(blk - AGG_BLKS, node, hist, gW, gb, out_causal);
    else if (blk < AGG_BLKS + 53) dev_qkv(blk - AGG_BLKS - 2, node, mha_in_W, mha_in_b, qkv);
    else                          dev_ent(blk - AGG_BLKS - 53, q_real, ent_W1, ent_b1, ent_W2, ent_b2, ent_scaled);
}

// ================= K2 (512 threads): attn | avg | mid_up quarters =================
// blocks: [0,108) attn, 108 avg, [109,217) mid_up quarters

__device__ void dev_attn(int blk, const float* __restrict__ qkv, float* __restrict__ o) {
    int h = blk / NS, q = blk % NS;
    int t = threadIdx.x;
    __shared__ float sc[NS];
    __shared__ float at[NS];
    if (t < NS) {
        const float* qrow = qkv + q * 960 + h * 80;
        const float* krow = qkv + t * 960 + EE + h * 80;
        float s = 0.0f;
        for (int d = 0; d < 80; ++d) s += qrow[d] * krow[d];
        sc[t] = s * 0.1118033988749895f;
    }
    __syncthreads();
    if (t < NS) {
        float m = -1e30f;
        for (int s2 = 0; s2 < NS; ++s2) m = fmaxf(m, sc[s2]);
        float sum = 0.0f;
        for (int s2 = 0; s2 < NS; ++s2) sum += expf(sc[s2] - m);
        at[t] = expf(sc[t] - m) / sum;
    }
    __syncthreads();
    if (t < 80) {
        float acc = 0.0f;
        for (int s2 = 0; s2 < NS; ++s2) acc += at[s2] * qkv[s2 * 960 + 2 * EE + h * 80 + t];
        o[q * EE + h * 80 + t] = acc;
    }
}

__device__ void dev_avg(const float* __restrict__ ent_scaled, float* __restrict__ avg) {
    __shared__ float aacc[8][64];
    int t = threadIdx.x;
    int col = t & 63, grp = t >> 6;
    float s = 0.0f;
    for (int p = grp; p < NPAIR; p += 8) s += ent_scaled[p * 64 + col];
    aacc[grp][col] = s;
    __syncthreads();
    if (t < 64) {
        float a = 0.0f;
        #pragma unroll
        for (int g = 0; g < 8; ++g) a += aacc[g][t];
        avg[t] = a / (float)NPAIR;
    }
}

__device__ void dev_mid_up(int rel, const float* __restrict__ partial, const float* __restrict__ agg_b,
                           const float* __restrict__ mid_states,
                           const float* __restrict__ W1, const float* __restrict__ b1,
                           const float* __restrict__ W2, const float* __restrict__ b2,
                           float* __restrict__ cf, float* __restrict__ hpm, int* __restrict__ ctrs) {
    int n = rel >> 2, p = rel & 3;
    __shared__ float combq[200];
    __shared__ float hp8[8][64];
    __shared__ float hid[64];
    __shared__ int flag;
    int t = threadIdx.x;
    if (p < 2) {
        if (t < 200) combq[t] = mid_states[n * 400 + p * 200 + t];
    } else {
        int j0 = (p - 2) * 200;
        if (t < 200) {
            float a = agg_b[n * 400 + j0 + t];
            const float* pp = partial + (size_t)(n * NCHUNK) * 400 + j0 + t;
            #pragma unroll 9
            for (int s = 0; s < NCHUNK; ++s) a += pp[s * 400];
            combq[t] = a;
        }
    }
    __syncthreads();
    {
        int h = t & 63, g = t >> 6;
        const float* w1 = W1 + (size_t)n * 51200 + (size_t)(p * 200) * 64;
        float hs = 0.0f;
        #pragma unroll 5
        for (int i = g * 25; i < g * 25 + 25; ++i) hs += combq[i] * w1[i * 64 + h];
        hp8[g][h] = hs;
    }
    __syncthreads();
    if (t < 64) {
        float hs = 0.0f;
        #pragma unroll
        for (int g = 0; g < 8; ++g) hs += hp8[g][t];
        hpm[(n * 4 + p) * 64 + t] = hs;
    }
    __syncthreads();
    if (t == 0) {
        int old = __hip_atomic_fetch_add(&ctrs[n], 1, __ATOMIC_ACQ_REL, __HIP_MEMORY_SCOPE_AGENT);
        flag = (old == 3);
    }
    __syncthreads();
    if (flag) {
        if (t < 64) {
            float hs = b1[n * 64 + t];
            #pragma unroll
            for (int pq = 0; pq < 4; ++pq) hs += hpm[(n * 4 + pq) * 64 + t];
            hid[t] = fmaxf(hs, 0.0f);
        }
        __syncthreads();
        const float* w2 = W2 + (size_t)n * 25600;
        if (t < 400) {
            float u = b2[n * 400 + t];
            #pragma unroll 8
            for (int k = 0; k < 64; ++k) u += hid[k] * w2[k * 400 + t];
            cf[n * 400 + t] = mid_states[n * 400 + t] + u;
        }
    }
}

__global__ __launch_bounds__(512) void k_stage2(
    const float* __restrict__ qkv, float* __restrict__ o,
    const float* __restrict__ ent_scaled, float* __restrict__ avg,
    const float* __restrict__ mid_partial, const float* __restrict__ mid_agg_b,
    const float* __restrict__ mid_states,
    const float* __restrict__ mid_up_W1, const float* __restrict__ mid_up_b1,
    const float* __restrict__ mid_up_W2, const float* __restrict__ mid_up_b2,
    float* __restrict__ cf, float* __restrict__ hpm, int* __restrict__ ctrs) {
    int blk = blockIdx.x;
    if (blk < 108)       dev_attn(blk, qkv, o);
    else if (blk == 108) dev_avg(ent_scaled, avg);
    else                 dev_mid_up(blk - 109, mid_partial, mid_agg_b, mid_states,
                                    mid_up_W1, mid_up_b1, mid_up_W2, mid_up_b2, cf, hpm, ctrs);
}

// ================= K3 (512 threads): proj | measured | root_agg (+inline root finish) =================
// blocks: [0,17) proj, [17,34) measured, [34,250) root_agg chunks (216 x 50 rows)

__device__ void dev_proj(int blk, const float* __restrict__ o, const float* __restrict__ W,
                         const float* __restrict__ b, float* __restrict__ outp) {
    int idx = blk * 512 + threadIdx.x;
    if (idx >= NS * EE) return;
    int i = idx / EE, c = idx % EE;
    const float4* orow = (const float4*)(o + i * EE);
    const float4* wr = (const float4*)(W + (size_t)c * EE);
    float acc = b[c];
    #pragma unroll 8
    for (int k = 0; k < 80; ++k) {
        float4 a = orow[k], w = wr[k];
        acc += a.x * w.x + a.y * w.y + a.z * w.z + a.w * w.w;
    }
    outp[idx] = 0.5f * acc;
}

__device__ void dev_measured(int blk, const float* __restrict__ q_real, const float* __restrict__ q_imag,
                             const float* __restrict__ avg, const float* __restrict__ W,
                             const float* __restrict__ b, float* __restrict__ out) {
    int idx = blk * 512 + threadIdx.x;
    if (idx >= NS * EE) return;
    int i = idx / EE, c = idx % EE;
    float acc = b[c];
    #pragma unroll 8
    for (int k = 0; k < 64; ++k) {
        float a = avg[k];
        acc += (q_real[i * 64 + k] + a) * W[k * EE + c];
        acc += (q_imag[i * 64 + k] + a) * W[(64 + k) * EE + c];
    }
    out[idx] = acc;
}

__device__ void dev_rootagg(int chunk, const float* __restrict__ W, const float* __restrict__ cf,
                            float* __restrict__ partial_r,
                            const float* __restrict__ agg_b, const float* __restrict__ root_state,
                            const float* __restrict__ W1, const float* __restrict__ b1,
                            const float* __restrict__ W2, const float* __restrict__ b2,
                            float* __restrict__ out, int* __restrict__ ctrs) {
    __shared__ float c_l[50];
    __shared__ __align__(16) float racc[5][400];
    __shared__ int flag;
    int t = threadIdx.x;
    if (t < 50) c_l[t] = cf[chunk * 50 + t];
    __syncthreads();
    if (t < 500) {
        int rp = t / 100, j4 = t % 100;
        const v4f* pA = (const v4f*)W + (size_t)(chunk * 50) * 100 + rp * 100 + j4;
        const v4f* pB = pA + 500;
        v4f a0 = (v4f)(0.0f), a1 = (v4f)(0.0f);
        #pragma unroll
        for (int rr = 0; rr < 5; ++rr) {
            v4f wa = __builtin_nontemporal_load(pA);
            v4f wb = __builtin_nontemporal_load(pB);
            a0 += c_l[10 * rr + rp] * wa;
            a1 += c_l[10 * rr + rp + 5] * wb;
            pA += 1000; pB += 1000;
        }
        a0 += a1;
        ((v4f*)&racc[rp][0])[j4] = a0;
    }
    __syncthreads();
    if (t < 400) {
        float a = racc[0][t] + racc[1][t] + racc[2][t] + racc[3][t] + racc[4][t];
        partial_r[chunk * 400 + t] = a;
    }
    __syncthreads();
    if (t == 0) {
        int old = __hip_atomic_fetch_add(&ctrs[31], 1, __ATOMIC_ACQ_REL, __HIP_MEMORY_SCOPE_AGENT);
        flag = (old == NRCHUNK - 1);
    }
    __syncthreads();
    if (!flag) return;

    // ---- last-arrival: full root update inline ----
    __shared__ float comb[800];
    __shared__ __align__(16) float s4f[2048];
    __shared__ float hid[64];
    if (t < 400) {
        float a = agg_b[t];
        const float* pp = partial_r + t;
        #pragma unroll 8
        for (int s = 0; s < NRCHUNK; ++s) a += pp[s * 400];
        comb[400 + t] = a;
        comb[t] = root_state[t];
    }
    __syncthreads();
    {
        const float4* W1f = (const float4*)W1;
        int i0 = t >> 4;
        float4 a4 = make_float4(0.f, 0.f, 0.f, 0.f);
        #pragma unroll
        for (int it = 0; it < 25; ++it) {
            float4 w = W1f[t + 512 * it];
            float cv = comb[i0 + 32 * it];
            a4.x += cv * w.x; a4.y += cv * w.y; a4.z += cv * w.z; a4.w += cv * w.w;
        }
        ((float4*)s4f)[t] = a4;
    }
    __syncthreads();
    if (t < 64) {
        float hs = b1[t];
        int r = t >> 2, c = t & 3;
        #pragma unroll 8
        for (int g = 0; g < 32; ++g) hs += s4f[(r + 16 * g) * 4 + c];
        hid[t] = fmaxf(hs, 0.0f);
    }
    __syncthreads();
    if (t < 400) {
        float u = b2[t];
        #pragma unroll 8
        for (int k = 0; k < 64; ++k) u += hid[k] * W2[k * 400 + t];
        out[t] = root_state[t] + u;
    }
}

__global__ __launch_bounds__(512) void k_stage3(
    const float* __restrict__ o, const float* __restrict__ mha_out_W,
    const float* __restrict__ mha_out_b, float* __restrict__ out_att,
    const float* __restrict__ q_real, const float* __restrict__ q_imag,
    const float* __restrict__ avg, const float* __restrict__ meas_W,
    const float* __restrict__ meas_b, float* __restrict__ out_meas,
    const float* __restrict__ root_agg_W, const float* __restrict__ cf,
    float* __restrict__ partial_r,
    const float* __restrict__ root_agg_b, const float* __restrict__ root_state,
    const float* __restrict__ root_up_W1, const float* __restrict__ root_up_b1,
    const float* __restrict__ root_up_W2, const float* __restrict__ root_up_b2,
    float* __restrict__ out_root, int* __restrict__ ctrs) {
    int blk = blockIdx.x;
    if (blk < 17)       dev_proj(blk, o, mha_out_W, mha_out_b, out_att);
    else if (blk < 34)  dev_measured(blk - 17, q_real, q_imag, avg, meas_W, meas_b, out_meas);
    else                dev_rootagg(blk - 34, root_agg_W, cf, partial_r,
                                    root_agg_b, root_state, root_up_W1, root_up_b1,
                                    root_up_W2, root_up_b2, out_root, ctrs);
}

extern "C" void kernel_launch(void* const* d_in, const int* in_sizes, int n_in,
                              void* d_out, int out_size, void* d_ws, size_t ws_size,
                              hipStream_t stream) {
    const float* node       = (const float*)d_in[0];
    const float* hist       = (const float*)d_in[1];
    const float* gW         = (const float*)d_in[2];
    const float* gb         = (const float*)d_in[3];
    const float* mha_in_W   = (const float*)d_in[4];
    const float* mha_in_b   = (const float*)d_in[5];
    const float* mha_out_W  = (const float*)d_in[6];
    const float* mha_out_b  = (const float*)d_in[7];
    const float* q_real     = (const float*)d_in[8];
    const float* q_imag     = (const float*)d_in[9];
    const float* ent_W1     = (const float*)d_in[10];
    const float* ent_b1     = (const float*)d_in[11];
    const float* ent_W2     = (const float*)d_in[12];
    const float* ent_b2     = (const float*)d_in[13];
    const float* meas_W     = (const float*)d_in[14];
    const float* meas_b     = (const float*)d_in[15];
    const float* leaf       = (const float*)d_in[16];
    const float* mid_states = (const float*)d_in[17];
    const float* root_state = (const float*)d_in[18];
    const float* mid_agg_W  = (const float*)d_in[19];
    const float* mid_agg_b  = (const float*)d_in[20];
    const float* root_agg_W = (const float*)d_in[21];
    const float* root_agg_b = (const float*)d_in[22];
    const float* mid_up_W1  = (const float*)d_in[23];
    const float* mid_up_b1  = (const float*)d_in[24];
    const float* mid_up_W2  = (const float*)d_in[25];
    const float* mid_up_b2  = (const float*)d_in[26];
    const float* root_up_W1 = (const float*)d_in[27];
    const float* root_up_b1 = (const float*)d_in[28];
    const float* root_up_W2 = (const float*)d_in[29];
    const float* root_up_b2 = (const float*)d_in[30];

    float* ws          = (float*)d_ws;
    float* qkv         = ws + WS_QKV;
    float* ent_scaled  = ws + WS_ENT;
    float* mid_partial = ws + WS_MIDP;
    float* cf          = ws + WS_CF;
    float* partial_r   = ws + WS_ROOTP;
    float* hpm         = ws + WS_HPM;
    int*   ctrs        = (int*)(ws + WS_CTR);
    float* o           = ws + WS_O;
    float* avg         = ws + WS_AVG;

    float* out        = (float*)d_out;
    float* out_causal = out;            // 729
    float* out_att    = out + 729;      // 8640
    float* out_meas   = out + 9369;     // 8640
    float* out_root   = out + 18009;    // 400

    hipLaunchKernelGGL(k_stage1, dim3(AGG_BLKS + 2 + 51 + 88), dim3(512), 0, stream,
                       mid_agg_W, leaf, node, hist, gW, gb, mha_in_W, mha_in_b,
                       q_real, ent_W1, ent_b1, ent_W2, ent_b2,
                       mid_partial, out_causal, qkv, ent_scaled, ctrs);

    hipLaunchKernelGGL(k_stage2, dim3(217), dim3(512), 0, stream,
                       qkv, o, ent_scaled, avg, mid_partial, mid_agg_b, mid_states,
                       mid_up_W1, mid_up_b1, mid_up_W2, mid_up_b2, cf, hpm, ctrs);

    hipLaunchKernelGGL(k_stage3, dim3(250), dim3(512), 0, stream,
                       o, mha_out_W, mha_out_b, out_att,
                       q_real, q_imag, avg, meas_W, meas_b, out_meas,
                       root_agg_W, cf, partial_r,
                       root_agg_b, root_state, root_up_W1, root_up_b1,
                       root_up_W2, root_up_b2, out_root, ctrs);
}

// Round 13
// 141.775 us; speedup vs baseline: 1.0798x; 1.0798x over previous
//
#include <hip/hip_runtime.h>
#include <math.h>

typedef float v4f __attribute__((ext_vector_type(4)));

// ---------------- geometry ----------------
#define SD 64
#define CC 64
#define EE 320
#define NS 27
#define NPAIR 351

#define NCHUNK 54
#define AGG_BLKS (27 * NCHUNK)   // 1458

// ws layout (floats)
#define WS_QKV   0                       // 27*960 = 25920
#define WS_ENT   25920                   // 351*64 = 22464 -> 48384
#define WS_MIDP  48384                   // 1458*2*400 = 1166400 -> 1214784
#define WS_CF    1214784                 // 10800 -> 1225584
#define WS_ROOTP 1225584                 // 108*400 = 43200 -> 1268784
#define WS_HPM   1268784                 // 27*4*64 = 6912 -> 1275696
#define WS_HPR   1275696                 // 256 -> 1275952
#define WS_CTR   1275968                 // 32 ints
// ctr indices: [0..26] per-node mid quarters, [30] root quarters

// ================= K1 (256 threads): mid_agg | granger | qkv | ent =================

__device__ void dev_mid_agg(int blk, const float* __restrict__ W,
                            const float* __restrict__ leaf, float* __restrict__ partial) {
    __shared__ float c_l[200];
    int n = blk / NCHUNK, chunk = blk % NCHUNK;
    int t = threadIdx.x;
    if (t < 200) c_l[t] = leaf[n * 10800 + chunk * 200 + t];
    __syncthreads();
    if (t < 200) {
        int rp = t / 100, j4 = t % 100;
        const v4f* Wr = (const v4f*)(W + (size_t)(n * 10800 + chunk * 200) * 400);
        v4f acc = (v4f)(0.0f);
        #pragma unroll 16
        for (int rr = 0; rr < 100; ++rr) {
            int r = 2 * rr + rp;
            v4f w = __builtin_nontemporal_load(&Wr[(size_t)r * 100 + j4]);
            acc += c_l[r] * w;
        }
        ((v4f*)(partial + (size_t)(blk * 2 + rp) * 400))[j4] = acc;
    }
}

__device__ void dev_granger(int blk, const float* __restrict__ x, const float* __restrict__ h,
                            const float* __restrict__ gW, const float* __restrict__ gb,
                            float* __restrict__ out) {
    int idx = blk * 256 + threadIdx.x;
    if (idx >= NS * NS) return;
    int i = idx / NS, j = idx % NS;
    const float* hr = h + j * 320;
    const float* xr = x + i * 320;
    float acc = gb[0];
    for (int k = 0; k < 320; ++k) acc += hr[k] * gW[k] + xr[k] * gW[320 + k];
    float sig = 1.0f / (1.0f + expf(-acc));
    out[idx] = (i == j) ? 0.0f : sig;
}

__device__ void dev_qkv(int blk, const float* __restrict__ x, const float* __restrict__ W,
                        const float* __restrict__ b, float* __restrict__ qkv) {
    int idx = blk * 256 + threadIdx.x;
    if (idx >= NS * 960) return;
    int i = idx / 960, c = idx % 960;
    const float4* xr = (const float4*)(x + i * 320);
    const float4* wr = (const float4*)(W + (size_t)c * 320);
    float acc = b[c];
    #pragma unroll 8
    for (int k = 0; k < 80; ++k) {
        float4 a = xr[k], w = wr[k];
        acc += a.x * w.x + a.y * w.y + a.z * w.z + a.w * w.w;
    }
    qkv[idx] = acc;
}

__device__ void dev_ent(int blk, const float* __restrict__ q_real,
                        const float* __restrict__ W1, const float* __restrict__ b1,
                        const float* __restrict__ W2, const float* __restrict__ b2,
                        float* __restrict__ ent_scaled) {
    __shared__ float comb[2][128];
    __shared__ float hid[2][64];
    int t = threadIdx.x;
    int sub = t >> 7, lt = t & 127;
    int p = blk * 2 + sub;
    bool pv = (p < NPAIR);
    bool valid = pv && (lt < 64);
    int i = 0, jj = 0;
    if (pv) {
        int rem = p;
        while (rem >= 26 - i) { rem -= 26 - i; ++i; }
        jj = i + 1 + rem;
    }
    float qa = 0.f, qb = 0.f;
    if (valid) { qa = q_real[i * CC + lt]; qb = q_real[jj * CC + lt]; }
    float sa = qa, sb = qb;
    #pragma unroll
    for (int off = 32; off; off >>= 1) { sa += __shfl_xor(sa, off); sb += __shfl_xor(sb, off); }
    float coupling = expf(-fabsf(sa - sb) / (500.0f + 1e-6f));
    if (valid) { comb[sub][lt] = qa; comb[sub][64 + lt] = qb; }
    __syncthreads();
    if (valid) {
        float hs = b1[lt];
        for (int ii = 0; ii < 128; ++ii) hs += comb[sub][ii] * W1[ii * 64 + lt];
        hid[sub][lt] = fmaxf(hs, 0.0f);
    }
    __syncthreads();
    if (valid) {
        float e = b2[lt];
        for (int k = 0; k < 64; ++k) e += hid[sub][k] * W2[k * 64 + lt];
        ent_scaled[p * 64 + lt] = e * coupling;
    }
}

__global__ __launch_bounds__(256) void k_stage1(
    const float* __restrict__ mid_agg_W, const float* __restrict__ leaf,
    const float* __restrict__ node, const float* __restrict__ hist,
    const float* __restrict__ gW, const float* __restrict__ gb,
    const float* __restrict__ mha_in_W, const float* __restrict__ mha_in_b,
    const float* __restrict__ q_real,
    const float* __restrict__ ent_W1, const float* __restrict__ ent_b1,
    const float* __restrict__ ent_W2, const float* __restrict__ ent_b2,
    float* __restrict__ mid_partial, float* __restrict__ out_causal,
    float* __restrict__ qkv, float* __restrict__ ent_scaled,
    int* __restrict__ ctrs) {
    int blk = blockIdx.x;
    if (blk == 0 && threadIdx.x >= 224) ctrs[threadIdx.x - 224] = 0;
    if (blk < AGG_BLKS)            dev_mid_agg(blk, mid_agg_W, leaf, mid_partial);
    else if (blk < AGG_BLKS + 3)   dev_granger(blk - AGG_BLKS, node, hist, gW, gb, out_causal);
    else if (blk < AGG_BLKS + 105) dev_qkv(blk - AGG_BLKS - 3, node, mha_in_W, mha_in_b, qkv);
    else                           dev_ent(blk - AGG_BLKS - 105, q_real, ent_W1, ent_b1, ent_W2, ent_b2, ent_scaled);
}

// ================= K2 (512 threads): attn | avg | mid_up quarters =================
// blocks: [0,108) attn, 108 avg, [109,217) mid_up quarters (27 nodes x 4)

__device__ void dev_attn(int blk, const float* __restrict__ qkv, float* __restrict__ o) {
    int h = blk / NS, q = blk % NS;
    int t = threadIdx.x;
    __shared__ float sc[NS];
    __shared__ float at[NS];
    if (t < NS) {
        const float* qrow = qkv + q * 960 + h * 80;
        const float* krow = qkv + t * 960 + EE + h * 80;
        float s = 0.0f;
        for (int d = 0; d < 80; ++d) s += qrow[d] * krow[d];
        sc[t] = s * 0.1118033988749895f;
    }
    __syncthreads();
    if (t < NS) {
        float m = -1e30f;
        for (int s2 = 0; s2 < NS; ++s2) m = fmaxf(m, sc[s2]);
        float sum = 0.0f;
        for (int s2 = 0; s2 < NS; ++s2) sum += expf(sc[s2] - m);
        at[t] = expf(sc[t] - m) / sum;
    }
    __syncthreads();
    if (t < 80) {
        float acc = 0.0f;
        for (int s2 = 0; s2 < NS; ++s2) acc += at[s2] * qkv[s2 * 960 + 2 * EE + h * 80 + t];
        o[q * EE + h * 80 + t] = acc;
    }
}

__device__ void dev_avg(const float* __restrict__ ent_scaled, float* __restrict__ avg) {
    __shared__ float aacc[8][64];
    int t = threadIdx.x;
    int col = t & 63, grp = t >> 6;
    float s = 0.0f;
    for (int p = grp; p < NPAIR; p += 8) s += ent_scaled[p * 64 + col];
    aacc[grp][col] = s;
    __syncthreads();
    if (t < 64) {
        float a = 0.0f;
        #pragma unroll
        for (int g = 0; g < 8; ++g) a += aacc[g][t];
        avg[t] = a / (float)NPAIR;
    }
}

__device__ void dev_mid_up(int rel, const float* __restrict__ partial, const float* __restrict__ agg_b,
                           const float* __restrict__ mid_states,
                           const float* __restrict__ W1, const float* __restrict__ b1,
                           const float* __restrict__ W2, const float* __restrict__ b2,
                           float* __restrict__ cf, float* __restrict__ hpm, int* __restrict__ ctrs) {
    int n = rel >> 2, p = rel & 3;
    __shared__ float combq[200];
    __shared__ float hp8[8][64];
    __shared__ float hid[64];
    __shared__ int flag;
    int t = threadIdx.x;
    if (p < 2) {
        if (t < 200) combq[t] = mid_states[n * 400 + p * 200 + t];
    } else {
        int j0 = (p - 2) * 200;
        if (t < 200) {
            float a = agg_b[n * 400 + j0 + t];
            const float* pp = partial + (size_t)(n * 108) * 400 + j0 + t;
            #pragma unroll 12
            for (int s = 0; s < 108; ++s) a += pp[s * 400];
            combq[t] = a;
        }
    }
    __syncthreads();
    {
        int h = t & 63, g = t >> 6;   // 8 groups of 25 rows
        const float* w1 = W1 + (size_t)n * 51200 + (size_t)(p * 200) * 64;
        float hs = 0.0f;
        #pragma unroll 5
        for (int i = g * 25; i < g * 25 + 25; ++i) hs += combq[i] * w1[i * 64 + h];
        hp8[g][h] = hs;
    }
    __syncthreads();
    if (t < 64) {
        float hs = 0.0f;
        #pragma unroll
        for (int g = 0; g < 8; ++g) hs += hp8[g][t];
        hpm[(n * 4 + p) * 64 + t] = hs;
    }
    __syncthreads();
    if (t == 0) {
        int old = __hip_atomic_fetch_add(&ctrs[n], 1, __ATOMIC_ACQ_REL, __HIP_MEMORY_SCOPE_AGENT);
        flag = (old == 3);
    }
    __syncthreads();
    if (flag) {
        if (t < 64) {
            float hs = b1[n * 64 + t];
            #pragma unroll
            for (int pq = 0; pq < 4; ++pq) hs += hpm[(n * 4 + pq) * 64 + t];
            hid[t] = fmaxf(hs, 0.0f);
        }
        __syncthreads();
        const float* w2 = W2 + (size_t)n * 25600;
        if (t < 400) {
            float u = b2[n * 400 + t];
            #pragma unroll 8
            for (int k = 0; k < 64; ++k) u += hid[k] * w2[k * 400 + t];
            cf[n * 400 + t] = mid_states[n * 400 + t] + u;
        }
    }
}

__global__ __launch_bounds__(512) void k_stage2(
    const float* __restrict__ qkv, float* __restrict__ o,
    const float* __restrict__ ent_scaled, float* __restrict__ avg,
    const float* __restrict__ mid_partial, const float* __restrict__ mid_agg_b,
    const float* __restrict__ mid_states,
    const float* __restrict__ mid_up_W1, const float* __restrict__ mid_up_b1,
    const float* __restrict__ mid_up_W2, const float* __restrict__ mid_up_b2,
    float* __restrict__ cf, float* __restrict__ hpm, int* __restrict__ ctrs) {
    int blk = blockIdx.x;
    if (blk < 108)       dev_attn(blk, qkv, o);
    else if (blk == 108) dev_avg(ent_scaled, avg);
    else                 dev_mid_up(blk - 109, mid_partial, mid_agg_b, mid_states,
                                    mid_up_W1, mid_up_b1, mid_up_W2, mid_up_b2, cf, hpm, ctrs);
}

// ================= K3 (512 threads): proj | measured | root_agg =================
// blocks: [0,17) proj, [17,34) measured, [34,142) root_agg chunks (108 x 100 rows)

__device__ void dev_proj(int blk, const float* __restrict__ o, const float* __restrict__ W,
                         const float* __restrict__ b, float* __restrict__ outp) {
    int idx = blk * 512 + threadIdx.x;
    if (idx >= NS * EE) return;
    int i = idx / EE, c = idx % EE;
    const float4* orow = (const float4*)(o + i * EE);
    const float4* wr = (const float4*)(W + (size_t)c * EE);
    float acc = b[c];
    #pragma unroll 8
    for (int k = 0; k < 80; ++k) {
        float4 a = orow[k], w = wr[k];
        acc += a.x * w.x + a.y * w.y + a.z * w.z + a.w * w.w;
    }
    outp[idx] = 0.5f * acc;
}

__device__ void dev_measured(int blk, const float* __restrict__ q_real, const float* __restrict__ q_imag,
                             const float* __restrict__ avg, const float* __restrict__ W,
                             const float* __restrict__ b, float* __restrict__ out) {
    int idx = blk * 512 + threadIdx.x;
    if (idx >= NS * EE) return;
    int i = idx / EE, c = idx % EE;
    float acc = b[c];
    #pragma unroll 8
    for (int k = 0; k < 64; ++k) {
        float a = avg[k];
        acc += (q_real[i * 64 + k] + a) * W[k * EE + c];
        acc += (q_imag[i * 64 + k] + a) * W[(64 + k) * EE + c];
    }
    out[idx] = acc;
}

__device__ void dev_rootagg(int chunk, const float* __restrict__ W, const float* __restrict__ cf,
                            float* __restrict__ partial_r) {
    __shared__ float racc[5][400];
    int t = threadIdx.x;
    int rp = t / 100, j4 = t % 100;   // rp in {0..4}
    if (rp < 5) {
        const float* c = cf + chunk * 100;
        const v4f* Wr = (const v4f*)W + (size_t)(chunk * 100) * 100;
        v4f acc = (v4f)(0.0f);
        #pragma unroll
        for (int rr = 0; rr < 20; ++rr) {
            int r = 5 * rr + rp;
            float cv = c[r];
            v4f w = __builtin_nontemporal_load(&Wr[(size_t)r * 100 + j4]);
            acc += cv * w;
        }
        racc[rp][j4 * 4 + 0] = acc.x;
        racc[rp][j4 * 4 + 1] = acc.y;
        racc[rp][j4 * 4 + 2] = acc.z;
        racc[rp][j4 * 4 + 3] = acc.w;
    }
    __syncthreads();
    if (t < 400) {
        float a = 0.0f;
        #pragma unroll
        for (int g = 0; g < 5; ++g) a += racc[g][t];
        partial_r[chunk * 400 + t] = a;
    }
}

__global__ __launch_bounds__(512) void k_stage3(
    const float* __restrict__ o, const float* __restrict__ mha_out_W,
    const float* __restrict__ mha_out_b, float* __restrict__ out_att,
    const float* __restrict__ q_real, const float* __restrict__ q_imag,
    const float* __restrict__ avg, const float* __restrict__ meas_W,
    const float* __restrict__ meas_b, float* __restrict__ out_meas,
    const float* __restrict__ root_agg_W, const float* __restrict__ cf,
    float* __restrict__ partial_r) {
    int blk = blockIdx.x;
    if (blk < 17)       dev_proj(blk, o, mha_out_W, mha_out_b, out_att);
    else if (blk < 34)  dev_measured(blk - 17, q_real, q_imag, avg, meas_W, meas_b, out_meas);
    else                dev_rootagg(blk - 34, root_agg_W, cf, partial_r);
}

// ================= K4 (512 threads, 4 blocks): root quarters + last-arrival finish =================
__global__ __launch_bounds__(512) void k_root(
    const float* __restrict__ partial_r, const float* __restrict__ agg_b,
    const float* __restrict__ root_state,
    const float* __restrict__ W1, const float* __restrict__ b1,
    const float* __restrict__ W2, const float* __restrict__ b2,
    float* __restrict__ out, float* __restrict__ hpr, int* __restrict__ ctrs) {
    int qd = blockIdx.x;
    __shared__ float combq[200];
    __shared__ float hp8[8][64];
    __shared__ float hid[64];
    __shared__ int flag;
    int t = threadIdx.x;
    if (qd < 2) {
        if (t < 200) combq[t] = root_state[qd * 200 + t];
    } else {
        int j0 = (qd - 2) * 200;
        if (t < 200) {
            float a = agg_b[j0 + t];
            const float* pp = partial_r + j0 + t;
            #pragma unroll 12
            for (int s = 0; s < 108; ++s) a += pp[s * 400];
            combq[t] = a;
        }
    }
    __syncthreads();
    {
        int h = t & 63, g = t >> 6;
        const float* w1 = W1 + (size_t)(qd * 200) * 64;
        float hs = 0.0f;
        #pragma unroll 5
        for (int i = g * 25; i < g * 25 + 25; ++i) hs += combq[i] * w1[i * 64 + h];
        hp8[g][h] = hs;
    }
    __syncthreads();
    if (t < 64) {
        float hs = 0.0f;
        #pragma unroll
        for (int g = 0; g < 8; ++g) hs += hp8[g][t];
        hpr[qd * 64 + t] = hs;
    }
    __syncthreads();
    if (t == 0) {
        int old = __hip_atomic_fetch_add(&ctrs[30], 1, __ATOMIC_ACQ_REL, __HIP_MEMORY_SCOPE_AGENT);
        flag = (old == 3);
    }
    __syncthreads();
    if (flag) {
        if (t < 64) {
            float hs = b1[t];
            #pragma unroll
            for (int pq = 0; pq < 4; ++pq) hs += hpr[pq * 64 + t];
            hid[t] = fmaxf(hs, 0.0f);
        }
        __syncthreads();
        if (t < 400) {
            float u = b2[t];
            #pragma unroll 8
            for (int k = 0; k < 64; ++k) u += hid[k] * W2[k * 400 + t];
            out[t] = root_state[t] + u;
        }
    }
}

extern "C" void kernel_launch(void* const* d_in, const int* in_sizes, int n_in,
                              void* d_out, int out_size, void* d_ws, size_t ws_size,
                              hipStream_t stream) {
    const float* node       = (const float*)d_in[0];
    const float* hist       = (const float*)d_in[1];
    const float* gW         = (const float*)d_in[2];
    const float* gb         = (const float*)d_in[3];
    const float* mha_in_W   = (const float*)d_in[4];
    const float* mha_in_b   = (const float*)d_in[5];
    const float* mha_out_W  = (const float*)d_in[6];
    const float* mha_out_b  = (const float*)d_in[7];
    const float* q_real     = (const float*)d_in[8];
    const float* q_imag     = (const float*)d_in[9];
    const float* ent_W1     = (const float*)d_in[10];
    const float* ent_b1     = (const float*)d_in[11];
    const float* ent_W2     = (const float*)d_in[12];
    const float* ent_b2     = (const float*)d_in[13];
    const float* meas_W     = (const float*)d_in[14];
    const float* meas_b     = (const float*)d_in[15];
    const float* leaf       = (const float*)d_in[16];
    const float* mid_states = (const float*)d_in[17];
    const float* root_state = (const float*)d_in[18];
    const float* mid_agg_W  = (const float*)d_in[19];
    const float* mid_agg_b  = (const float*)d_in[20];
    const float* root_agg_W = (const float*)d_in[21];
    const float* root_agg_b = (const float*)d_in[22];
    const float* mid_up_W1  = (const float*)d_in[23];
    const float* mid_up_b1  = (const float*)d_in[24];
    const float* mid_up_W2  = (const float*)d_in[25];
    const float* mid_up_b2  = (const float*)d_in[26];
    const float* root_up_W1 = (const float*)d_in[27];
    const float* root_up_b1 = (const float*)d_in[28];
    const float* root_up_W2 = (const float*)d_in[29];
    const float* root_up_b2 = (const float*)d_in[30];

    float* ws          = (float*)d_ws;
    float* qkv         = ws + WS_QKV;
    float* ent_scaled  = ws + WS_ENT;
    float* mid_partial = ws + WS_MIDP;
    float* cf          = ws + WS_CF;
    float* partial_r   = ws + WS_ROOTP;
    float* hpm         = ws + WS_HPM;
    float* hpr         = ws + WS_HPR;
    int*   ctrs        = (int*)(ws + WS_CTR);

    float* o = ws + WS_CTR + 32;   // 27*320 = 8640 floats
    float* avg = o + 8640;         // 64 floats

    float* out        = (float*)d_out;
    float* out_causal = out;            // 729
    float* out_att    = out + 729;      // 8640
    float* out_meas   = out + 9369;     // 8640
    float* out_root   = out + 18009;    // 400

    hipLaunchKernelGGL(k_stage1, dim3(AGG_BLKS + 105 + 176), dim3(256), 0, stream,
                       mid_agg_W, leaf, node, hist, gW, gb, mha_in_W, mha_in_b,
                       q_real, ent_W1, ent_b1, ent_W2, ent_b2,
                       mid_partial, out_causal, qkv, ent_scaled, ctrs);

    hipLaunchKernelGGL(k_stage2, dim3(217), dim3(512), 0, stream,
                       qkv, o, ent_scaled, avg, mid_partial, mid_agg_b, mid_states,
                       mid_up_W1, mid_up_b1, mid_up_W2, mid_up_b2, cf, hpm, ctrs);

    hipLaunchKernelGGL(k_stage3, dim3(142), dim3(512), 0, stream,
                       o, mha_out_W, mha_out_b, out_att,
                       q_real, q_imag, avg, meas_W, meas_b, out_meas,
                       root_agg_W, cf, partial_r);

    hipLaunchKernelGGL(k_root, dim3(4), dim3(512), 0, stream,
                       partial_r, root_agg_b, root_state,
                       root_up_W1, root_up_b1, root_up_W2, root_up_b2, out_root, hpr, ctrs);
}